// Round 11
// baseline (542.400 us; speedup 1.0000x reference)
//
#include <hip/hip_runtime.h>
#include <hip/hip_bf16.h>
#include <hip/hip_fp16.h>

typedef __bf16 bf16_t;
typedef __bf16 bf16x8 __attribute__((ext_vector_type(8)));
typedef float f32x4 __attribute__((ext_vector_type(4)));

#define SCALE_ 0.125f   // 64^-0.5
#define BATCH 4
#define NSEQ 2048
#define DMODEL 512
#define HEADS 8
#define DHEAD 64
#define QKVN 1536
#define NN ((size_t)NSEQ * NSEQ)

// LDS-only barrier: does NOT drain vmcnt, so prefetched global loads stay in
// flight across it. All cross-thread communication in attn is via LDS;
// global loads land in private VGPRs (compiler inserts vmcnt waits at use).
#define BAR() asm volatile("s_waitcnt lgkmcnt(0)\n\ts_barrier" ::: "memory")

__device__ __forceinline__ void gload_lds16(const void* g, void* l) {
  __builtin_amdgcn_global_load_lds((const __attribute__((address_space(1))) void*)g,
                                   (__attribute__((address_space(3))) void*)l, 16, 0, 0);
}

__device__ __forceinline__ f32x4 mfma16(bf16x8 a, bf16x8 b, f32x4 c) {
  return __builtin_amdgcn_mfma_f32_16x16x32_bf16(a, b, c, 0, 0, 0);
}

// packed half2 max via ISA (avoids __hmax2 overload ambiguity with bf16 hdrs)
__device__ __forceinline__ int pkmax_f16(int a, int b) {
  int d;
  asm("v_pk_max_f16 %0, %1, %2" : "=v"(d) : "v"(a), "v"(b));
  return d;
}

// VALU cross-lane move within 16-lane DPP rows (row_ror:N -> ctrl 0x120|N).
template<int CTRL>
__device__ __forceinline__ int movdpp(int x) {
  return __builtin_amdgcn_update_dpp(0, x, CTRL, 0xf, 0xf, true);
}

// ---------------- convert kernels ----------------
__global__ __launch_bounds__(256) void cvt_bf16_kernel(const float* __restrict__ in,
                                                       bf16_t* __restrict__ out, int n4) {
  int i = blockIdx.x * 256 + threadIdx.x;
  if (i < n4) {
    float4 v = ((const float4*)in)[i];
    union { bf16_t b[4]; uint2 u; } pk;
    pk.b[0] = (bf16_t)v.x; pk.b[1] = (bf16_t)v.y;
    pk.b[2] = (bf16_t)v.z; pk.b[3] = (bf16_t)v.w;
    ((uint2*)out)[i] = pk.u;
  }
}

// in[R][C] fp32 -> out[C][R] bf16, LDS-tiled so both sides coalesce.
// grid: (C/64, R/64), block 256
__global__ __launch_bounds__(256) void cvt_transpose_kernel(const float* __restrict__ in,
                                                            bf16_t* __restrict__ out, int R, int C) {
  __shared__ float tile[64][65];
  const int r0 = blockIdx.y * 64, c0 = blockIdx.x * 64;
  const int tx = threadIdx.x & 63, tg = threadIdx.x >> 6;
#pragma unroll
  for (int i = 0; i < 16; i++) {
    int rr = tg * 16 + i;
    tile[rr][tx] = in[(size_t)(r0 + rr) * C + c0 + tx];
  }
  __syncthreads();
#pragma unroll
  for (int i = 0; i < 16; i++) {
    int cc = tg * 16 + i;
    out[(size_t)(c0 + cc) * R + r0 + tx] = (bf16_t)tile[tx][cc];
  }
}

// ---------------- GEMM: C[M,N] = A[M,K] * Bt[N,K]^T (+bias) ----------------
// m97-style; VSPLIT: QKV-GEMM blocks with n0 >= 1024 (V third) write output
// TRANSPOSED to vt via an LDS repack (64B-contiguous segments per vt row).
template<int BIAS, int OUTF32, int VSPLIT>
__global__ __launch_bounds__(256) void gemm128_kernel(const bf16_t* __restrict__ A,
    const bf16_t* __restrict__ Bt, void* __restrict__ Cout,
    const float* __restrict__ bias, bf16_t* __restrict__ vt, int M, int N, int K) {
  __shared__ __align__(16) bf16_t SM[2][128 * 64];   // As | Bs, contiguous 32KB
  bf16_t* As = SM[0];
  bf16_t* Bs = SM[1];
  const int tid = threadIdx.x;
  const int w = tid >> 6, lane = tid & 63, quad = lane >> 4, l16 = lane & 15;
  const int wm = w & 1, wn = w >> 1;
  const int m0 = blockIdx.x * 128, n0 = blockIdx.y * 128;
  f32x4 acc[4][4] = {};
  int srow[4], scg[4];
#pragma unroll
  for (int t = 0; t < 4; t++) {
    int s = (w * 4 + t) * 64 + lane;
    srow[t] = s >> 3;
    scg[t] = (s & 7) ^ (srow[t] & 7);
  }
  for (int k0 = 0; k0 < K; k0 += 64) {
#pragma unroll
    for (int t = 0; t < 4; t++) {
      gload_lds16(&A[(size_t)(m0 + srow[t]) * K + k0 + scg[t] * 8], &As[(w * 4 + t) * 512]);
      gload_lds16(&Bt[(size_t)(n0 + srow[t]) * K + k0 + scg[t] * 8], &Bs[(w * 4 + t) * 512]);
    }
    __syncthreads();   // full drain needed: DMA completion tracked by vmcnt
    bf16x8 af[4][2], bfr[4][2];
#pragma unroll
    for (int mt = 0; mt < 4; mt++) {
      int row = wm * 64 + mt * 16 + l16;
#pragma unroll
      for (int kh = 0; kh < 2; kh++)
        af[mt][kh] = *(const bf16x8*)&As[(row * 8 + ((kh * 4 + quad) ^ (row & 7))) * 8];
    }
#pragma unroll
    for (int nt = 0; nt < 4; nt++) {
      int row = wn * 64 + nt * 16 + l16;
#pragma unroll
      for (int kh = 0; kh < 2; kh++)
        bfr[nt][kh] = *(const bf16x8*)&Bs[(row * 8 + ((kh * 4 + quad) ^ (row & 7))) * 8];
    }
#pragma unroll
    for (int mt = 0; mt < 4; mt++)
#pragma unroll
      for (int nt = 0; nt < 4; nt++) {
        acc[mt][nt] = mfma16(af[mt][0], bfr[nt][0], acc[mt][nt]);
        acc[mt][nt] = mfma16(af[mt][1], bfr[nt][1], acc[mt][nt]);
      }
    __syncthreads();
  }
  if (VSPLIT && n0 >= 1024) {
    // ---- transposed V epilogue via LDS repack: T[hd_local][n_local] ----
    bf16_t* T = &SM[0][0];   // 128*128 bf16 = 32KB; main-loop reads are done
#pragma unroll
    for (int nt = 0; nt < 4; nt++) {
      int hdl = wn * 64 + nt * 16 + l16;
#pragma unroll
      for (int mt = 0; mt < 4; mt++) {
        int nloc = wm * 64 + mt * 16 + quad * 4;
        union { bf16_t e[4]; uint2 u; } pk;
#pragma unroll
        for (int rr = 0; rr < 4; rr++) pk.e[rr] = (bf16_t)acc[mt][nt][rr];
        *(uint2*)&T[hdl * 128 + nloc] = pk.u;
      }
    }
    __syncthreads();
    const int bb = m0 >> 11, nn0 = m0 & 2047;
#pragma unroll
    for (int pass = 0; pass < 2; pass++) {
      const int r = pass * 64 + (tid >> 2);
      const size_t gb = ((size_t)(bb * 512 + (n0 - 1024) + r)) * NSEQ + nn0;
#pragma unroll
      for (int i = 0; i < 4; i++) {
        int c = i * 32 + (tid & 3) * 8;
        *(uint4*)&vt[gb + c] = *(const uint4*)&T[r * 128 + c];
      }
    }
    return;
  }
#pragma unroll
  for (int nt = 0; nt < 4; nt++) {
    int col = n0 + wn * 64 + nt * 16 + l16;
    float bv = BIAS ? bias[col] : 0.0f;
#pragma unroll
    for (int mt = 0; mt < 4; mt++) {
#pragma unroll
      for (int rr = 0; rr < 4; rr++) {
        int row = m0 + wm * 64 + mt * 16 + quad * 4 + rr;
        float v = acc[mt][nt][rr] + bv;
        if (OUTF32) ((float*)Cout)[(size_t)row * N + col] = v;
        else        ((bf16_t*)Cout)[(size_t)row * N + col] = (bf16_t)v;
      }
    }
  }
}

// ---------------- fused flash attention with conv-bias, j-SPLIT ----------------
// R11: grid 2048. bid = (h*2+jh)*128 + b*32 + it. Each block processes HALF
// the j-range (16 tiles of 64). Rationale: the 1024-block grid was the
// occupancy limiter (4 blocks/CU demand, 37% achieved, no pipe >55%).
// 2048 blocks -> LDS-capped 5 blocks/CU resident (20 waves). Adjacent blocks
// = consecutive it of one (b,h,jh): K/V stream reuse preserved (R9 lesson).
// Output: UNNORMALIZED o (f32) + per-row (m,l) -> merge_kernel combines.
// Body = R10 (verified): vt-staged V, DPP max, ones-MFMA row-sum.
__global__ __launch_bounds__(256, 4) void attn_kernel(const bf16_t* __restrict__ qkv,
    const bf16_t* __restrict__ vt,
    const float* __restrict__ cd, const float* __restrict__ rel_w,
    const float* __restrict__ rel_b, float* __restrict__ opart,
    float2* __restrict__ mls) {
  __shared__ __align__(16) bf16_t Ks[64][72];   // K tile: [jrel][d]
  __shared__ __align__(16) bf16_t Vts[64][72];  // V^T tile: [d][j], col XOR-swizzled
  __shared__ __align__(16) bf16_t Ps[64][72];   // P: [qrow][j], col XOR-swizzled
  const int tid = threadIdx.x;
  const int w = tid >> 6, lane = tid & 63, quad = lane >> 4, l16 = lane & 15;
  const int bid = blockIdx.x;
  const int hj = bid >> 7, h = hj >> 1, jh = hj & 1;
  const int b = (bid >> 5) & 3, it = bid & 31;
  const int jbase = jh * 1024;   // element offset of this block's j-half

  const size_t qoff = (size_t)(b * NSEQ + it * 64 + w * 16 + l16) * QKVN + h * DHEAD;
  bf16x8 q0 = *(const bf16x8*)&qkv[qoff + quad * 8];
  bf16x8 q1 = *(const bf16x8*)&qkv[qoff + 32 + quad * 8];

  const float rw0 = rel_w[h * 3 + 0], rw1 = rel_w[h * 3 + 1], rw2 = rel_w[h * 3 + 2];
  const float rb = rel_b[h];

  bf16x8 ones;
#pragma unroll
  for (int e = 0; e < 8; e++) ones[e] = (bf16_t)1.0f;

  f32x4 o[4] = {};
  float m_r[4], l_r[4];
#pragma unroll
  for (int r = 0; r < 4; r++) { m_r[r] = -1e30f; l_r[r] = 0.0f; }

  const int sr = tid >> 3, sg = tid & 7;
  const size_t kbase = (size_t)b * NSEQ * QKVN + DMODEL + h * DHEAD;
  const size_t vtb = (size_t)(b * HEADS + h) * 64 * NSEQ;
  const int vc0 = (sg ^ ((sr >> 3) & 3)) * 8;   // same for rows sr and sr+32

  const int row0 = it * 64 + w * 16 + quad * 4;
  const float* cdp = cd + (size_t)b * 3 * NN + (size_t)row0 * NSEQ + l16;
  float biasr[4][4];
#define LOADBIAS(JTA) do { const int jb_ = (JTA) * 64;                                 \
  _Pragma("unroll") for (int ct_ = 0; ct_ < 4; ct_++)                                  \
  _Pragma("unroll") for (int r_ = 0; r_ < 4; r_++) {                                   \
    size_t ci_ = (size_t)r_ * NSEQ + jb_ + ct_ * 16;                                   \
    biasr[ct_][r_] = fmaf(rw0, cdp[ci_],                                               \
                     fmaf(rw1, cdp[ci_ + NN], fmaf(rw2, cdp[ci_ + 2 * NN], rb)));      \
  } } while (0)

  // prologue: this half's K/V tile 0 -> regs, bias -> regs
  uint4 k0r, k1r, v0r, v1r;
  {
    const bf16_t* p = &qkv[kbase + (size_t)(jbase + sr) * QKVN + sg * 8];
    k0r = *(const uint4*)p;
    k1r = *(const uint4*)(p + 32 * QKVN);
    const bf16_t* pv = &vt[vtb + (size_t)sr * NSEQ + jbase + sg * 8];
    v0r = *(const uint4*)pv;
    v1r = *(const uint4*)(pv + 32 * NSEQ);
  }
  LOADBIAS(jh * 16);

  for (int jt = 0; jt < 16; jt++) {
    // ---- staged regs -> LDS ----
    *(uint4*)&Ks[sr][sg * 8]      = k0r;
    *(uint4*)&Ks[sr + 32][sg * 8] = k1r;
    *(uint4*)&Vts[sr][vc0]        = v0r;
    *(uint4*)&Vts[sr + 32][vc0]   = v1r;
    BAR();

    // ---- issue next tile's K/V loads ----
    if (jt < 15) {
      const bf16_t* p = &qkv[kbase + (size_t)(jbase + (jt + 1) * 64 + sr) * QKVN + sg * 8];
      k0r = *(const uint4*)p;
      k1r = *(const uint4*)(p + 32 * QKVN);
      const bf16_t* pv = &vt[vtb + (size_t)sr * NSEQ + jbase + (jt + 1) * 64 + sg * 8];
      v0r = *(const uint4*)pv;
      v1r = *(const uint4*)(pv + 32 * NSEQ);
    }

    // ---- S = Q * K^T ----
    f32x4 s[4] = {};
#pragma unroll
    for (int ct = 0; ct < 4; ct++) {
      bf16x8 b0 = *(const bf16x8*)&Ks[ct * 16 + l16][quad * 8];
      bf16x8 b1 = *(const bf16x8*)&Ks[ct * 16 + l16][32 + quad * 8];
      s[ct] = mfma16(q0, b0, s[ct]);
      s[ct] = mfma16(q1, b1, s[ct]);
    }

    // ---- scale + bias (prefetched), then prefetch next bias ----
#pragma unroll
    for (int ct = 0; ct < 4; ct++)
#pragma unroll
      for (int r = 0; r < 4; r++)
        s[ct][r] = s[ct][r] * SCALE_ + biasr[ct][r];
    if (jt < 15) LOADBIAS(jh * 16 + jt + 1);

    // ---- online softmax max: in-lane over ct, DPP row_ror over l16 ----
    float mx[4];
#pragma unroll
    for (int r = 0; r < 4; r++)
      mx[r] = fmaxf(fmaxf(s[0][r], s[1][r]), fmaxf(s[2][r], s[3][r]));
    {
      union { __half h[2]; int i; } u01, u23;
      u01.h[0] = __float2half(mx[0]); u01.h[1] = __float2half(mx[1]);
      u23.h[0] = __float2half(mx[2]); u23.h[1] = __float2half(mx[3]);
      u01.i = pkmax_f16(u01.i, movdpp<0x128>(u01.i));   // row_ror:8
      u23.i = pkmax_f16(u23.i, movdpp<0x128>(u23.i));
      u01.i = pkmax_f16(u01.i, movdpp<0x124>(u01.i));   // row_ror:4
      u23.i = pkmax_f16(u23.i, movdpp<0x124>(u23.i));
      u01.i = pkmax_f16(u01.i, movdpp<0x122>(u01.i));   // row_ror:2
      u23.i = pkmax_f16(u23.i, movdpp<0x122>(u23.i));
      u01.i = pkmax_f16(u01.i, movdpp<0x121>(u01.i));   // row_ror:1
      u23.i = pkmax_f16(u23.i, movdpp<0x121>(u23.i));
      mx[0] = __half2float(u01.h[0]); mx[1] = __half2float(u01.h[1]);
      mx[2] = __half2float(u23.h[0]); mx[3] = __half2float(u23.h[1]);
    }
    float alpha[4];
#pragma unroll
    for (int r = 0; r < 4; r++) {
      float mnew = fmaxf(m_r[r], mx[r]);   // half-max underestimates by <=1ulp: safe
      alpha[r] = __expf(m_r[r] - mnew);
      m_r[r] = mnew;
#pragma unroll
      for (int ct = 0; ct < 4; ct++)
        s[ct][r] = __expf(s[ct][r] - mnew);
#pragma unroll
      for (int dt = 0; dt < 4; dt++) o[dt][r] *= alpha[r];
    }

    // ---- P: C-layout -> LDS (swizzled) -> A-layout (wave-private slice) ----
#pragma unroll
    for (int ct = 0; ct < 4; ct++)
#pragma unroll
      for (int rr = 0; rr < 4; rr++)
        Ps[w * 16 + quad * 4 + rr][(ct * 16 + l16) ^ (quad << 3)] = (bf16_t)s[ct][rr];

    const int psw = ((l16 >> 2) & 3) << 3;
    bf16x8 p0 = *(const bf16x8*)&Ps[w * 16 + l16][(quad * 8) ^ psw];
    bf16x8 p1 = *(const bf16x8*)&Ps[w * 16 + l16][32 + ((quad * 8) ^ psw)];
#pragma unroll
    for (int dt = 0; dt < 4; dt++) {
      const int row = dt * 16 + l16;
      const int vsw = ((row >> 3) & 3) << 3;
      bf16x8 v0 = *(const bf16x8*)&Vts[row][(quad * 8) ^ vsw];
      bf16x8 v1 = *(const bf16x8*)&Vts[row][32 + ((quad * 8) ^ vsw)];
      o[dt] = mfma16(p0, v0, o[dt]);
      o[dt] = mfma16(p1, v1, o[dt]);
    }
    // ---- row-sum of P via ones-MFMA ----
    {
      f32x4 ls = {};
      ls = mfma16(p0, ones, ls);
      ls = mfma16(p1, ones, ls);
#pragma unroll
      for (int r = 0; r < 4; r++) l_r[r] = l_r[r] * alpha[r] + ls[r];
    }
    BAR();   // readers of Ks/Vts done before next iteration's writes
  }

  // ---- epilogue: UNNORMALIZED o (f32) + per-row stats ----
  float* ob = opart + (size_t)bid * 4096;
#pragma unroll
  for (int dt = 0; dt < 4; dt++) {
    int col = dt * 16 + l16;
#pragma unroll
    for (int rr = 0; rr < 4; rr++) {
      int rl = w * 16 + quad * 4 + rr;
      ob[rl * 64 + col] = o[dt][rr];
    }
  }
  if (l16 == 0) {
#pragma unroll
    for (int r = 0; r < 4; r++) {
      int rl = w * 16 + quad * 4 + r;
      mls[(size_t)bid * 64 + rl] = make_float2(m_r[r], l_r[r]);
    }
  }
#undef LOADBIAS
}

// ---------------- flash split-j merge ----------------
// out[gr][c] = (e0*o0 + e1*o1) / (e0*l0 + e1*l1), e_i = exp(m_i - max)
// grid: 8192*512/4/256 = 4096 blocks. Each thread: 4 consecutive cols.
__global__ __launch_bounds__(256) void merge_kernel(const float* __restrict__ opart,
    const float2* __restrict__ mls, bf16_t* __restrict__ ao) {
  int qi = blockIdx.x * 256 + threadIdx.x;
  int gr = qi >> 7;                 // global row 0..8191
  int c4 = (qi & 127) << 2;         // col 0..508 step 4
  int h = c4 >> 6, d = c4 & 63;
  int b = gr >> 11, n = gr & 2047, it = n >> 6, rl = n & 63;
  int bid0 = h * 256 + b * 32 + it;         // jh=0
  int bid1 = bid0 + 128;                    // jh=1
  float2 s0 = mls[(size_t)bid0 * 64 + rl];
  float2 s1 = mls[(size_t)bid1 * 64 + rl];
  float m = fmaxf(s0.x, s1.x);
  float e0 = __expf(s0.x - m), e1 = __expf(s1.x - m);
  float rinv = 1.0f / (s0.y * e0 + s1.y * e1);
  f32x4 o0 = *(const f32x4*)&opart[(size_t)bid0 * 4096 + rl * 64 + d];
  f32x4 o1 = *(const f32x4*)&opart[(size_t)bid1 * 4096 + rl * 64 + d];
  union { bf16_t e[4]; uint2 u; } pk;
#pragma unroll
  for (int i = 0; i < 4; i++)
    pk.e[i] = (bf16_t)((o0[i] * e0 + o1[i] * e1) * rinv);
  *(uint2*)&ao[(size_t)gr * DMODEL + c4] = pk.u;
}

// ---------------- launch ----------------
extern "C" void kernel_launch(void* const* d_in, const int* in_sizes, int n_in,
                              void* d_out, int out_size, void* d_ws, size_t ws_size,
                              hipStream_t stream) {
  const float* x     = (const float*)d_in[0];
  const float* cd    = (const float*)d_in[1];
  const float* Wqkv  = (const float*)d_in[2];
  const float* Wout  = (const float*)d_in[3];
  const float* bout  = (const float*)d_in[4];
  const float* rel_w = (const float*)d_in[5];
  const float* rel_b = (const float*)d_in[6];
  float* out = (float*)d_out;

  char* ws = (char*)d_ws;
  const size_t M = (size_t)BATCH * NSEQ;                 // 8192
  bf16_t* xb    = (bf16_t*)ws;                           // 8 MB
  bf16_t* WqkvT = (bf16_t*)(ws + 8388608);
  bf16_t* WoutT = (bf16_t*)(ws + 8388608 + 1572864);
  bf16_t* qkv   = (bf16_t*)(ws + 10485760);
  bf16_t* ao    = (bf16_t*)(ws + 35651584);
  bf16_t* vtw   = (bf16_t*)(ws + 44040192);
  float*  opart = (float*)(ws + 52428800);               // 2048*4096*4 = 32 MB
  float2* mls   = (float2*)(ws + 85983232);              // 2048*64*8 = 1 MB

  cvt_bf16_kernel<<<(int)(M * DMODEL / 4 / 256), 256, 0, stream>>>(x, xb, (int)(M * DMODEL / 4));
  cvt_transpose_kernel<<<dim3(QKVN / 64, DMODEL / 64), 256, 0, stream>>>(Wqkv, WqkvT, DMODEL, QKVN);
  cvt_transpose_kernel<<<dim3(DMODEL / 64, DMODEL / 64), 256, 0, stream>>>(Wout, WoutT, DMODEL, DMODEL);

  // QKV GEMM: Q,K columns -> qkv; V columns (blockIdx.y >= 8) -> vtw transposed
  gemm128_kernel<0, 0, 1><<<dim3(M / 128, QKVN / 128), 256, 0, stream>>>(
      xb, WqkvT, (void*)qkv, nullptr, vtw, (int)M, QKVN, DMODEL);

  attn_kernel<<<2048, 256, 0, stream>>>(qkv, vtw, cd, rel_w, rel_b, opart, mls);

  merge_kernel<<<4096, 256, 0, stream>>>(opart, mls, ao);

  gemm128_kernel<1, 1, 0><<<dim3(M / 128, DMODEL / 128), 256, 0, stream>>>(
      ao, WoutT, (void*)out, bout, nullptr, (int)M, DMODEL, DMODEL);
}

// Round 12
// 441.793 us; speedup vs baseline: 1.2277x; 1.2277x over previous
//
#include <hip/hip_runtime.h>
#include <hip/hip_bf16.h>
#include <hip/hip_fp16.h>

typedef __bf16 bf16_t;
typedef __bf16 bf16x8 __attribute__((ext_vector_type(8)));
typedef float f32x4 __attribute__((ext_vector_type(4)));

#define SCALE_ 0.125f   // 64^-0.5
#define BATCH 4
#define NSEQ 2048
#define DMODEL 512
#define HEADS 8
#define DHEAD 64
#define QKVN 1536
#define NN ((size_t)NSEQ * NSEQ)

// LDS-only barrier: does NOT drain vmcnt, so prefetched global loads stay in
// flight across it. All cross-thread communication in attn is via LDS;
// global loads land in private VGPRs (compiler inserts vmcnt waits at use).
#define BAR() asm volatile("s_waitcnt lgkmcnt(0)\n\ts_barrier" ::: "memory")

__device__ __forceinline__ void gload_lds16(const void* g, void* l) {
  __builtin_amdgcn_global_load_lds((const __attribute__((address_space(1))) void*)g,
                                   (__attribute__((address_space(3))) void*)l, 16, 0, 0);
}

__device__ __forceinline__ f32x4 mfma16(bf16x8 a, bf16x8 b, f32x4 c) {
  return __builtin_amdgcn_mfma_f32_16x16x32_bf16(a, b, c, 0, 0, 0);
}

// packed half2 max via ISA (avoids __hmax2 overload ambiguity with bf16 hdrs)
__device__ __forceinline__ int pkmax_f16(int a, int b) {
  int d;
  asm("v_pk_max_f16 %0, %1, %2" : "=v"(d) : "v"(a), "v"(b));
  return d;
}

// ---------------- convert kernels ----------------
__global__ __launch_bounds__(256) void cvt_bf16_kernel(const float* __restrict__ in,
                                                       bf16_t* __restrict__ out, int n4) {
  int i = blockIdx.x * 256 + threadIdx.x;
  if (i < n4) {
    float4 v = ((const float4*)in)[i];
    union { bf16_t b[4]; uint2 u; } pk;
    pk.b[0] = (bf16_t)v.x; pk.b[1] = (bf16_t)v.y;
    pk.b[2] = (bf16_t)v.z; pk.b[3] = (bf16_t)v.w;
    ((uint2*)out)[i] = pk.u;
  }
}

// in[R][C] fp32 -> out[C][R] bf16, LDS-tiled so both sides coalesce.
// grid: (C/64, R/64), block 256
__global__ __launch_bounds__(256) void cvt_transpose_kernel(const float* __restrict__ in,
                                                            bf16_t* __restrict__ out, int R, int C) {
  __shared__ float tile[64][65];
  const int r0 = blockIdx.y * 64, c0 = blockIdx.x * 64;
  const int tx = threadIdx.x & 63, tg = threadIdx.x >> 6;
#pragma unroll
  for (int i = 0; i < 16; i++) {
    int rr = tg * 16 + i;
    tile[rr][tx] = in[(size_t)(r0 + rr) * C + c0 + tx];
  }
  __syncthreads();
#pragma unroll
  for (int i = 0; i < 16; i++) {
    int cc = tg * 16 + i;
    out[(size_t)(c0 + cc) * R + r0 + tx] = (bf16_t)tile[tx][cc];
  }
}

// ---------------- GEMM: C[M,N] = A[M,K] * Bt[N,K]^T (+bias) ----------------
// m97-style: 128x128 tile, BK=64, global_load_lds width=16, 4 waves (2x2),
// 4x4 16x16 acc per wave. LDS layout in 16B "slots": slot s holds row=s>>3,
// cg=(s&7)^(row&7) (XOR swizzle applied on the GLOBAL side of the DMA since
// the LDS side is fixed to lane*16B).
template<int BIAS, int OUTF32>
__global__ __launch_bounds__(256) void gemm128_kernel(const bf16_t* __restrict__ A,
    const bf16_t* __restrict__ Bt, void* __restrict__ Cout,
    const float* __restrict__ bias, int M, int N, int K) {
  __shared__ __align__(16) bf16_t As[128 * 64];
  __shared__ __align__(16) bf16_t Bs[128 * 64];
  const int tid = threadIdx.x;
  const int w = tid >> 6, lane = tid & 63, quad = lane >> 4, l16 = lane & 15;
  const int wm = w & 1, wn = w >> 1;
  const int m0 = blockIdx.x * 128, n0 = blockIdx.y * 128;
  f32x4 acc[4][4] = {};
  int srow[4], scg[4];
#pragma unroll
  for (int t = 0; t < 4; t++) {
    int s = (w * 4 + t) * 64 + lane;
    srow[t] = s >> 3;
    scg[t] = (s & 7) ^ (srow[t] & 7);
  }
  for (int k0 = 0; k0 < K; k0 += 64) {
#pragma unroll
    for (int t = 0; t < 4; t++) {
      gload_lds16(&A[(size_t)(m0 + srow[t]) * K + k0 + scg[t] * 8], &As[(w * 4 + t) * 512]);
      gload_lds16(&Bt[(size_t)(n0 + srow[t]) * K + k0 + scg[t] * 8], &Bs[(w * 4 + t) * 512]);
    }
    __syncthreads();   // full drain needed: DMA completion tracked by vmcnt
    bf16x8 af[4][2], bfr[4][2];
#pragma unroll
    for (int mt = 0; mt < 4; mt++) {
      int row = wm * 64 + mt * 16 + l16;
#pragma unroll
      for (int kh = 0; kh < 2; kh++)
        af[mt][kh] = *(const bf16x8*)&As[(row * 8 + ((kh * 4 + quad) ^ (row & 7))) * 8];
    }
#pragma unroll
    for (int nt = 0; nt < 4; nt++) {
      int row = wn * 64 + nt * 16 + l16;
#pragma unroll
      for (int kh = 0; kh < 2; kh++)
        bfr[nt][kh] = *(const bf16x8*)&Bs[(row * 8 + ((kh * 4 + quad) ^ (row & 7))) * 8];
    }
#pragma unroll
    for (int mt = 0; mt < 4; mt++)
#pragma unroll
      for (int nt = 0; nt < 4; nt++) {
        acc[mt][nt] = mfma16(af[mt][0], bfr[nt][0], acc[mt][nt]);
        acc[mt][nt] = mfma16(af[mt][1], bfr[nt][1], acc[mt][nt]);
      }
    __syncthreads();
  }
#pragma unroll
  for (int nt = 0; nt < 4; nt++) {
    int col = n0 + wn * 64 + nt * 16 + l16;
    float bv = BIAS ? bias[col] : 0.0f;
#pragma unroll
    for (int mt = 0; mt < 4; mt++) {
#pragma unroll
      for (int rr = 0; rr < 4; rr++) {
        int row = m0 + wm * 64 + mt * 16 + quad * 4 + rr;
        float v = acc[mt][nt][rr] + bv;
        if (OUTF32) ((float*)Cout)[(size_t)row * N + col] = v;
        else        ((bf16_t*)Cout)[(size_t)row * N + col] = (bf16_t)v;
      }
    }
  }
}

// ---------------- fused flash attention with conv-bias ----------------
// grid: 1024 blocks; bid = h*128 + b*32 + it (head-siblings -> same XCD)
// R12 = R5 exactly (best measured: 441.4 us total, attn 189): single-buffer
// LDS, two BARs/jt, R0 bias path, with softmax reductions on the cheap path:
//  - row-SUM via ones-MFMA on the P fragments (0 bpermutes);
//    denominator sums the same bf16-rounded P used in the numerator.
//  - row-MAX via packed-half2 butterfly (8 bpermutes), v_pk_max_f16 asm.
__global__ __launch_bounds__(256, 4) void attn_kernel(const bf16_t* __restrict__ qkv,
    const float* __restrict__ cd, const float* __restrict__ rel_w,
    const float* __restrict__ rel_b, bf16_t* __restrict__ ao) {
  __shared__ __align__(16) bf16_t Ks[64][72];   // K tile: [jrel][d]
  __shared__ __align__(16) bf16_t Vts[64][72];  // V^T tile: [d][j], col XOR-swizzled
  __shared__ __align__(16) bf16_t Ps[64][72];   // P: [qrow][j], col XOR-swizzled
  const int tid = threadIdx.x;
  const int w = tid >> 6, lane = tid & 63, quad = lane >> 4, l16 = lane & 15;
  const int bid = blockIdx.x;
  const int h = bid >> 7, b = (bid >> 5) & 3, it = bid & 31;

  const size_t qoff = (size_t)(b * NSEQ + it * 64 + w * 16 + l16) * QKVN + h * DHEAD;
  bf16x8 q0 = *(const bf16x8*)&qkv[qoff + quad * 8];
  bf16x8 q1 = *(const bf16x8*)&qkv[qoff + 32 + quad * 8];

  const float rw0 = rel_w[h * 3 + 0], rw1 = rel_w[h * 3 + 1], rw2 = rel_w[h * 3 + 2];
  const float rb = rel_b[h];

  bf16x8 ones;
#pragma unroll
  for (int e = 0; e < 8; e++) ones[e] = (bf16_t)1.0f;

  f32x4 o[4] = {};
  float m_r[4], l_r[4];
#pragma unroll
  for (int r = 0; r < 4; r++) { m_r[r] = -1e30f; l_r[r] = 0.0f; }

  const int sr = tid >> 3, sg = tid & 7;
  const size_t kbase = (size_t)b * NSEQ * QKVN + DMODEL + h * DHEAD;

  // cd -> bias combined at load: 16 live regs instead of 48
  const int row0 = it * 64 + w * 16 + quad * 4;
  const float* cdp = cd + (size_t)b * 3 * NN + (size_t)row0 * NSEQ + l16;
  float biasr[4][4];
#define LOADBIAS(JT) do { const int jb_ = (JT) * 64;                                   \
  _Pragma("unroll") for (int ct_ = 0; ct_ < 4; ct_++)                                  \
  _Pragma("unroll") for (int r_ = 0; r_ < 4; r_++) {                                   \
    size_t ci_ = (size_t)r_ * NSEQ + jb_ + ct_ * 16;                                   \
    biasr[ct_][r_] = fmaf(rw0, cdp[ci_],                                               \
                     fmaf(rw1, cdp[ci_ + NN], fmaf(rw2, cdp[ci_ + 2 * NN], rb)));      \
  } } while (0)

  // prologue: K/V tile 0 -> regs, bias tile 0 -> regs
  uint4 k0r, k1r, v0r, v1r;
  {
    const bf16_t* p = &qkv[kbase + (size_t)sr * QKVN + sg * 8];
    k0r = *(const uint4*)p;               v0r = *(const uint4*)(p + DMODEL);
    k1r = *(const uint4*)(p + 32 * QKVN); v1r = *(const uint4*)(p + 32 * QKVN + DMODEL);
  }
  LOADBIAS(0);

  for (int jt = 0; jt < 32; jt++) {
    // ---- staged regs -> LDS (loads had a full compute phase to land) ----
    *(uint4*)&Ks[sr][sg * 8]      = k0r;
    *(uint4*)&Ks[sr + 32][sg * 8] = k1r;
    {
      union { bf16_t e[8]; uint4 u; } va, vb; va.u = v0r; vb.u = v1r;
      const int pc = sr ^ ((sg & 3) << 3);
#pragma unroll
      for (int e2 = 0; e2 < 8; e2++) {
        Vts[sg * 8 + e2][pc]      = va.e[e2];
        Vts[sg * 8 + e2][pc + 32] = vb.e[e2];
      }
    }
    BAR();

    // ---- issue next tile's K/V loads (in flight across the whole phase) ----
    if (jt < 31) {
      const bf16_t* p = &qkv[kbase + (size_t)((jt + 1) * 64 + sr) * QKVN + sg * 8];
      k0r = *(const uint4*)p;               v0r = *(const uint4*)(p + DMODEL);
      k1r = *(const uint4*)(p + 32 * QKVN); v1r = *(const uint4*)(p + 32 * QKVN + DMODEL);
    }

    // ---- S = Q * K^T ----
    f32x4 s[4] = {};
#pragma unroll
    for (int ct = 0; ct < 4; ct++) {
      bf16x8 b0 = *(const bf16x8*)&Ks[ct * 16 + l16][quad * 8];
      bf16x8 b1 = *(const bf16x8*)&Ks[ct * 16 + l16][32 + quad * 8];
      s[ct] = mfma16(q0, b0, s[ct]);
      s[ct] = mfma16(q1, b1, s[ct]);
    }

    // ---- scale + bias (prefetched), then prefetch next bias ----
#pragma unroll
    for (int ct = 0; ct < 4; ct++)
#pragma unroll
      for (int r = 0; r < 4; r++)
        s[ct][r] = s[ct][r] * SCALE_ + biasr[ct][r];
    if (jt < 31) LOADBIAS(jt + 1);

    // ---- online softmax max: in-lane over ct, packed-half2 over l16 ----
    float mx[4];
#pragma unroll
    for (int r = 0; r < 4; r++)
      mx[r] = fmaxf(fmaxf(s[0][r], s[1][r]), fmaxf(s[2][r], s[3][r]));
    {
      union { __half h[2]; int i; } u01, u23;
      u01.h[0] = __float2half(mx[0]); u01.h[1] = __float2half(mx[1]);
      u23.h[0] = __float2half(mx[2]); u23.h[1] = __float2half(mx[3]);
#pragma unroll
      for (int off = 8; off >= 1; off >>= 1) {
        u01.i = pkmax_f16(u01.i, __shfl_xor(u01.i, off, 64));
        u23.i = pkmax_f16(u23.i, __shfl_xor(u23.i, off, 64));
      }
      mx[0] = __half2float(u01.h[0]); mx[1] = __half2float(u01.h[1]);
      mx[2] = __half2float(u23.h[0]); mx[3] = __half2float(u23.h[1]);
    }
    float alpha[4];
#pragma unroll
    for (int r = 0; r < 4; r++) {
      float mnew = fmaxf(m_r[r], mx[r]);   // half-max underestimates by <=1ulp: safe
      alpha[r] = __expf(m_r[r] - mnew);
      m_r[r] = mnew;
#pragma unroll
      for (int ct = 0; ct < 4; ct++)
        s[ct][r] = __expf(s[ct][r] - mnew);
#pragma unroll
      for (int dt = 0; dt < 4; dt++) o[dt][r] *= alpha[r];
    }

    // ---- P: C-layout -> LDS (swizzled) -> A-layout (wave-private slice) ----
#pragma unroll
    for (int ct = 0; ct < 4; ct++)
#pragma unroll
      for (int rr = 0; rr < 4; rr++)
        Ps[w * 16 + quad * 4 + rr][(ct * 16 + l16) ^ (quad << 3)] = (bf16_t)s[ct][rr];

    const int psw = ((l16 >> 2) & 3) << 3;
    bf16x8 p0 = *(const bf16x8*)&Ps[w * 16 + l16][(quad * 8) ^ psw];
    bf16x8 p1 = *(const bf16x8*)&Ps[w * 16 + l16][32 + ((quad * 8) ^ psw)];
#pragma unroll
    for (int dt = 0; dt < 4; dt++) {
      const int row = dt * 16 + l16;
      const int vsw = ((row >> 3) & 3) << 3;
      bf16x8 v0 = *(const bf16x8*)&Vts[row][(quad * 8) ^ vsw];
      bf16x8 v1 = *(const bf16x8*)&Vts[row][32 + ((quad * 8) ^ vsw)];
      o[dt] = mfma16(p0, v0, o[dt]);
      o[dt] = mfma16(p1, v1, o[dt]);
    }
    // ---- row-sum of P via ones-MFMA (replaces 16 sum bpermutes) ----
    {
      f32x4 ls = {};
      ls = mfma16(p0, ones, ls);
      ls = mfma16(p1, ones, ls);
#pragma unroll
      for (int r = 0; r < 4; r++) l_r[r] = l_r[r] * alpha[r] + ls[r];
    }
    BAR();   // readers of Ks/Vts done before next iteration's writes
  }

  // ---- epilogue ----
#pragma unroll
  for (int dt = 0; dt < 4; dt++) {
    int col = h * DHEAD + dt * 16 + l16;
#pragma unroll
    for (int rr = 0; rr < 4; rr++) {
      int row = b * NSEQ + it * 64 + w * 16 + quad * 4 + rr;
      ao[(size_t)row * DMODEL + col] = (bf16_t)(o[dt][rr] / l_r[rr]);
    }
  }
#undef LOADBIAS
}

// ---------------- launch ----------------
extern "C" void kernel_launch(void* const* d_in, const int* in_sizes, int n_in,
                              void* d_out, int out_size, void* d_ws, size_t ws_size,
                              hipStream_t stream) {
  const float* x     = (const float*)d_in[0];
  const float* cd    = (const float*)d_in[1];
  const float* Wqkv  = (const float*)d_in[2];
  const float* Wout  = (const float*)d_in[3];
  const float* bout  = (const float*)d_in[4];
  const float* rel_w = (const float*)d_in[5];
  const float* rel_b = (const float*)d_in[6];
  float* out = (float*)d_out;

  char* ws = (char*)d_ws;
  const size_t M = (size_t)BATCH * NSEQ;                 // 8192
  bf16_t* xb    = (bf16_t*)ws;                           // 8 MB
  bf16_t* WqkvT = (bf16_t*)(ws + 8388608);
  bf16_t* WoutT = (bf16_t*)(ws + 8388608 + 1572864);
  bf16_t* qkv   = (bf16_t*)(ws + 8388608 + 1572864 + 524288);
  bf16_t* ao    = (bf16_t*)(ws + 8388608 + 1572864 + 524288 + 25165824);

  cvt_bf16_kernel<<<(int)(M * DMODEL / 4 / 256), 256, 0, stream>>>(x, xb, (int)(M * DMODEL / 4));
  cvt_transpose_kernel<<<dim3(QKVN / 64, DMODEL / 64), 256, 0, stream>>>(Wqkv, WqkvT, DMODEL, QKVN);
  cvt_transpose_kernel<<<dim3(DMODEL / 64, DMODEL / 64), 256, 0, stream>>>(Wout, WoutT, DMODEL, DMODEL);

  gemm128_kernel<0, 0><<<dim3(M / 128, QKVN / 128), 256, 0, stream>>>(
      xb, WqkvT, (void*)qkv, nullptr, (int)M, QKVN, DMODEL);

  attn_kernel<<<BATCH * 32 * HEADS, 256, 0, stream>>>(qkv, cd, rel_w, rel_b, ao);

  gemm128_kernel<1, 1><<<dim3(M / 128, DMODEL / 128), 256, 0, stream>>>(
      ao, WoutT, (void*)out, bout, (int)M, DMODEL, DMODEL);
}

// Round 13
// 440.014 us; speedup vs baseline: 1.2327x; 1.0040x over previous
//
#include <hip/hip_runtime.h>
#include <hip/hip_bf16.h>
#include <hip/hip_fp16.h>

typedef __bf16 bf16_t;
typedef __bf16 bf16x8 __attribute__((ext_vector_type(8)));
typedef float f32x4 __attribute__((ext_vector_type(4)));

#define SCALE_ 0.125f   // 64^-0.5
#define BATCH 4
#define NSEQ 2048
#define DMODEL 512
#define HEADS 8
#define DHEAD 64
#define QKVN 1536
#define NN ((size_t)NSEQ * NSEQ)

// LDS-only barrier: does NOT drain vmcnt, so prefetched global loads stay in
// flight across it. All cross-thread communication in attn is via LDS;
// global loads land in private VGPRs (compiler inserts vmcnt waits at use).
#define BAR() asm volatile("s_waitcnt lgkmcnt(0)\n\ts_barrier" ::: "memory")

__device__ __forceinline__ void gload_lds16(const void* g, void* l) {
  __builtin_amdgcn_global_load_lds((const __attribute__((address_space(1))) void*)g,
                                   (__attribute__((address_space(3))) void*)l, 16, 0, 0);
}

__device__ __forceinline__ f32x4 mfma16(bf16x8 a, bf16x8 b, f32x4 c) {
  return __builtin_amdgcn_mfma_f32_16x16x32_bf16(a, b, c, 0, 0, 0);
}

// packed half2 max via ISA (avoids __hmax2 overload ambiguity with bf16 hdrs)
__device__ __forceinline__ int pkmax_f16(int a, int b) {
  int d;
  asm("v_pk_max_f16 %0, %1, %2" : "=v"(d) : "v"(a), "v"(b));
  return d;
}

// ---------------- convert kernels ----------------
__global__ __launch_bounds__(256) void cvt_bf16_kernel(const float* __restrict__ in,
                                                       bf16_t* __restrict__ out, int n4) {
  int i = blockIdx.x * 256 + threadIdx.x;
  if (i < n4) {
    float4 v = ((const float4*)in)[i];
    union { bf16_t b[4]; uint2 u; } pk;
    pk.b[0] = (bf16_t)v.x; pk.b[1] = (bf16_t)v.y;
    pk.b[2] = (bf16_t)v.z; pk.b[3] = (bf16_t)v.w;
    ((uint2*)out)[i] = pk.u;
  }
}

// in[R][C] fp32 -> out[C][R] bf16, LDS-tiled so both sides coalesce.
// grid: (C/64, R/64), block 256
__global__ __launch_bounds__(256) void cvt_transpose_kernel(const float* __restrict__ in,
                                                            bf16_t* __restrict__ out, int R, int C) {
  __shared__ float tile[64][65];
  const int r0 = blockIdx.y * 64, c0 = blockIdx.x * 64;
  const int tx = threadIdx.x & 63, tg = threadIdx.x >> 6;
#pragma unroll
  for (int i = 0; i < 16; i++) {
    int rr = tg * 16 + i;
    tile[rr][tx] = in[(size_t)(r0 + rr) * C + c0 + tx];
  }
  __syncthreads();
#pragma unroll
  for (int i = 0; i < 16; i++) {
    int cc = tg * 16 + i;
    out[(size_t)(c0 + cc) * R + r0 + tx] = (bf16_t)tile[tx][cc];
  }
}

// ---------------- GEMM: C[M,N] = A[M,K] * Bt[N,K]^T (+bias) ----------------
// m97-style, templated tile BM x BN (both multiples of 32; waves 2x2, each
// covering (BM/2)x(BN/2)). BK=64, global_load_lds width=16. LDS layout in 16B
// "slots": slot s holds row=s>>3, cg=(s&7)^(row&7) (XOR swizzle applied on
// the GLOBAL side of the DMA since the LDS side is fixed to lane*16B).
// R13: smaller tiles for the thin-K GEMMs -> more blocks -> latency hiding
// (gemm1 was 256 blocks = 1 block/CU: every K-step barrier-drain exposed).
template<int BM, int BN, int BIAS, int OUTF32>
__global__ __launch_bounds__(256) void gemm_kernel(const bf16_t* __restrict__ A,
    const bf16_t* __restrict__ Bt, void* __restrict__ Cout,
    const float* __restrict__ bias, int M, int N, int K) {
  constexpr int AT = BM / 32;          // A staging slots (16B) per thread
  constexpr int BT = BN / 32;          // B staging slots per thread
  constexpr int HM = BM / 2;           // per-wave M extent
  constexpr int HN = BN / 2;           // per-wave N extent
  constexpr int MT = HM / 16;          // 16x16 frags per wave in M
  constexpr int NT = HN / 16;          // 16x16 frags per wave in N
  __shared__ __align__(16) bf16_t As[BM * 64];
  __shared__ __align__(16) bf16_t Bs[BN * 64];
  const int tid = threadIdx.x;
  const int w = tid >> 6, lane = tid & 63, quad = lane >> 4, l16 = lane & 15;
  const int wm = w & 1, wn = w >> 1;
  const int m0 = blockIdx.x * BM, n0 = blockIdx.y * BN;
  f32x4 acc[MT][NT] = {};
  int srowA[AT], scgA[AT], srowB[BT], scgB[BT];
#pragma unroll
  for (int t = 0; t < AT; t++) {
    int s = (w * AT + t) * 64 + lane;
    srowA[t] = s >> 3;
    scgA[t] = (s & 7) ^ (srowA[t] & 7);
  }
#pragma unroll
  for (int t = 0; t < BT; t++) {
    int s = (w * BT + t) * 64 + lane;
    srowB[t] = s >> 3;
    scgB[t] = (s & 7) ^ (srowB[t] & 7);
  }
  for (int k0 = 0; k0 < K; k0 += 64) {
#pragma unroll
    for (int t = 0; t < AT; t++)
      gload_lds16(&A[(size_t)(m0 + srowA[t]) * K + k0 + scgA[t] * 8], &As[(w * AT + t) * 512]);
#pragma unroll
    for (int t = 0; t < BT; t++)
      gload_lds16(&Bt[(size_t)(n0 + srowB[t]) * K + k0 + scgB[t] * 8], &Bs[(w * BT + t) * 512]);
    __syncthreads();   // full drain needed: DMA completion tracked by vmcnt
    bf16x8 af[MT][2], bfr[NT][2];
#pragma unroll
    for (int mt = 0; mt < MT; mt++) {
      int row = wm * HM + mt * 16 + l16;
#pragma unroll
      for (int kh = 0; kh < 2; kh++)
        af[mt][kh] = *(const bf16x8*)&As[(row * 8 + ((kh * 4 + quad) ^ (row & 7))) * 8];
    }
#pragma unroll
    for (int nt = 0; nt < NT; nt++) {
      int row = wn * HN + nt * 16 + l16;
#pragma unroll
      for (int kh = 0; kh < 2; kh++)
        bfr[nt][kh] = *(const bf16x8*)&Bs[(row * 8 + ((kh * 4 + quad) ^ (row & 7))) * 8];
    }
#pragma unroll
    for (int mt = 0; mt < MT; mt++)
#pragma unroll
      for (int nt = 0; nt < NT; nt++) {
        acc[mt][nt] = mfma16(af[mt][0], bfr[nt][0], acc[mt][nt]);
        acc[mt][nt] = mfma16(af[mt][1], bfr[nt][1], acc[mt][nt]);
      }
    __syncthreads();
  }
#pragma unroll
  for (int nt = 0; nt < NT; nt++) {
    int col = n0 + wn * HN + nt * 16 + l16;
    float bv = BIAS ? bias[col] : 0.0f;
#pragma unroll
    for (int mt = 0; mt < MT; mt++) {
#pragma unroll
      for (int rr = 0; rr < 4; rr++) {
        int row = m0 + wm * HM + mt * 16 + quad * 4 + rr;
        float v = acc[mt][nt][rr] + bv;
        if (OUTF32) ((float*)Cout)[(size_t)row * N + col] = v;
        else        ((bf16_t*)Cout)[(size_t)row * N + col] = (bf16_t)v;
      }
    }
  }
}

// ---------------- fused flash attention with conv-bias ----------------
// grid: 1024 blocks; bid = h*128 + b*32 + it (head-siblings -> same XCD)
// R13 attn = R12/R5 exactly (best measured, reproduced twice: 441 us total,
// attn ~190): single-buffer LDS, two BARs/jt, R0 bias path,
//  - row-SUM via ones-MFMA on the P fragments (0 bpermutes);
//  - row-MAX via packed-half2 butterfly (8 bpermutes), v_pk_max_f16 asm.
__global__ __launch_bounds__(256, 4) void attn_kernel(const bf16_t* __restrict__ qkv,
    const float* __restrict__ cd, const float* __restrict__ rel_w,
    const float* __restrict__ rel_b, bf16_t* __restrict__ ao) {
  __shared__ __align__(16) bf16_t Ks[64][72];   // K tile: [jrel][d]
  __shared__ __align__(16) bf16_t Vts[64][72];  // V^T tile: [d][j], col XOR-swizzled
  __shared__ __align__(16) bf16_t Ps[64][72];   // P: [qrow][j], col XOR-swizzled
  const int tid = threadIdx.x;
  const int w = tid >> 6, lane = tid & 63, quad = lane >> 4, l16 = lane & 15;
  const int bid = blockIdx.x;
  const int h = bid >> 7, b = (bid >> 5) & 3, it = bid & 31;

  const size_t qoff = (size_t)(b * NSEQ + it * 64 + w * 16 + l16) * QKVN + h * DHEAD;
  bf16x8 q0 = *(const bf16x8*)&qkv[qoff + quad * 8];
  bf16x8 q1 = *(const bf16x8*)&qkv[qoff + 32 + quad * 8];

  const float rw0 = rel_w[h * 3 + 0], rw1 = rel_w[h * 3 + 1], rw2 = rel_w[h * 3 + 2];
  const float rb = rel_b[h];

  bf16x8 ones;
#pragma unroll
  for (int e = 0; e < 8; e++) ones[e] = (bf16_t)1.0f;

  f32x4 o[4] = {};
  float m_r[4], l_r[4];
#pragma unroll
  for (int r = 0; r < 4; r++) { m_r[r] = -1e30f; l_r[r] = 0.0f; }

  const int sr = tid >> 3, sg = tid & 7;
  const size_t kbase = (size_t)b * NSEQ * QKVN + DMODEL + h * DHEAD;

  // cd -> bias combined at load: 16 live regs instead of 48
  const int row0 = it * 64 + w * 16 + quad * 4;
  const float* cdp = cd + (size_t)b * 3 * NN + (size_t)row0 * NSEQ + l16;
  float biasr[4][4];
#define LOADBIAS(JT) do { const int jb_ = (JT) * 64;                                   \
  _Pragma("unroll") for (int ct_ = 0; ct_ < 4; ct_++)                                  \
  _Pragma("unroll") for (int r_ = 0; r_ < 4; r_++) {                                   \
    size_t ci_ = (size_t)r_ * NSEQ + jb_ + ct_ * 16;                                   \
    biasr[ct_][r_] = fmaf(rw0, cdp[ci_],                                               \
                     fmaf(rw1, cdp[ci_ + NN], fmaf(rw2, cdp[ci_ + 2 * NN], rb)));      \
  } } while (0)

  // prologue: K/V tile 0 -> regs, bias tile 0 -> regs
  uint4 k0r, k1r, v0r, v1r;
  {
    const bf16_t* p = &qkv[kbase + (size_t)sr * QKVN + sg * 8];
    k0r = *(const uint4*)p;               v0r = *(const uint4*)(p + DMODEL);
    k1r = *(const uint4*)(p + 32 * QKVN); v1r = *(const uint4*)(p + 32 * QKVN + DMODEL);
  }
  LOADBIAS(0);

  for (int jt = 0; jt < 32; jt++) {
    // ---- staged regs -> LDS (loads had a full compute phase to land) ----
    *(uint4*)&Ks[sr][sg * 8]      = k0r;
    *(uint4*)&Ks[sr + 32][sg * 8] = k1r;
    {
      union { bf16_t e[8]; uint4 u; } va, vb; va.u = v0r; vb.u = v1r;
      const int pc = sr ^ ((sg & 3) << 3);
#pragma unroll
      for (int e2 = 0; e2 < 8; e2++) {
        Vts[sg * 8 + e2][pc]      = va.e[e2];
        Vts[sg * 8 + e2][pc + 32] = vb.e[e2];
      }
    }
    BAR();

    // ---- issue next tile's K/V loads (in flight across the whole phase) ----
    if (jt < 31) {
      const bf16_t* p = &qkv[kbase + (size_t)((jt + 1) * 64 + sr) * QKVN + sg * 8];
      k0r = *(const uint4*)p;               v0r = *(const uint4*)(p + DMODEL);
      k1r = *(const uint4*)(p + 32 * QKVN); v1r = *(const uint4*)(p + 32 * QKVN + DMODEL);
    }

    // ---- S = Q * K^T ----
    f32x4 s[4] = {};
#pragma unroll
    for (int ct = 0; ct < 4; ct++) {
      bf16x8 b0 = *(const bf16x8*)&Ks[ct * 16 + l16][quad * 8];
      bf16x8 b1 = *(const bf16x8*)&Ks[ct * 16 + l16][32 + quad * 8];
      s[ct] = mfma16(q0, b0, s[ct]);
      s[ct] = mfma16(q1, b1, s[ct]);
    }

    // ---- scale + bias (prefetched), then prefetch next bias ----
#pragma unroll
    for (int ct = 0; ct < 4; ct++)
#pragma unroll
      for (int r = 0; r < 4; r++)
        s[ct][r] = s[ct][r] * SCALE_ + biasr[ct][r];
    if (jt < 31) LOADBIAS(jt + 1);

    // ---- online softmax max: in-lane over ct, packed-half2 over l16 ----
    float mx[4];
#pragma unroll
    for (int r = 0; r < 4; r++)
      mx[r] = fmaxf(fmaxf(s[0][r], s[1][r]), fmaxf(s[2][r], s[3][r]));
    {
      union { __half h[2]; int i; } u01, u23;
      u01.h[0] = __float2half(mx[0]); u01.h[1] = __float2half(mx[1]);
      u23.h[0] = __float2half(mx[2]); u23.h[1] = __float2half(mx[3]);
#pragma unroll
      for (int off = 8; off >= 1; off >>= 1) {
        u01.i = pkmax_f16(u01.i, __shfl_xor(u01.i, off, 64));
        u23.i = pkmax_f16(u23.i, __shfl_xor(u23.i, off, 64));
      }
      mx[0] = __half2float(u01.h[0]); mx[1] = __half2float(u01.h[1]);
      mx[2] = __half2float(u23.h[0]); mx[3] = __half2float(u23.h[1]);
    }
    float alpha[4];
#pragma unroll
    for (int r = 0; r < 4; r++) {
      float mnew = fmaxf(m_r[r], mx[r]);   // half-max underestimates by <=1ulp: safe
      alpha[r] = __expf(m_r[r] - mnew);
      m_r[r] = mnew;
#pragma unroll
      for (int ct = 0; ct < 4; ct++)
        s[ct][r] = __expf(s[ct][r] - mnew);
#pragma unroll
      for (int dt = 0; dt < 4; dt++) o[dt][r] *= alpha[r];
    }

    // ---- P: C-layout -> LDS (swizzled) -> A-layout (wave-private slice) ----
#pragma unroll
    for (int ct = 0; ct < 4; ct++)
#pragma unroll
      for (int rr = 0; rr < 4; rr++)
        Ps[w * 16 + quad * 4 + rr][(ct * 16 + l16) ^ (quad << 3)] = (bf16_t)s[ct][rr];

    const int psw = ((l16 >> 2) & 3) << 3;
    bf16x8 p0 = *(const bf16x8*)&Ps[w * 16 + l16][(quad * 8) ^ psw];
    bf16x8 p1 = *(const bf16x8*)&Ps[w * 16 + l16][32 + ((quad * 8) ^ psw)];
#pragma unroll
    for (int dt = 0; dt < 4; dt++) {
      const int row = dt * 16 + l16;
      const int vsw = ((row >> 3) & 3) << 3;
      bf16x8 v0 = *(const bf16x8*)&Vts[row][(quad * 8) ^ vsw];
      bf16x8 v1 = *(const bf16x8*)&Vts[row][32 + ((quad * 8) ^ vsw)];
      o[dt] = mfma16(p0, v0, o[dt]);
      o[dt] = mfma16(p1, v1, o[dt]);
    }
    // ---- row-sum of P via ones-MFMA (replaces 16 sum bpermutes) ----
    {
      f32x4 ls = {};
      ls = mfma16(p0, ones, ls);
      ls = mfma16(p1, ones, ls);
#pragma unroll
      for (int r = 0; r < 4; r++) l_r[r] = l_r[r] * alpha[r] + ls[r];
    }
    BAR();   // readers of Ks/Vts done before next iteration's writes
  }

  // ---- epilogue ----
#pragma unroll
  for (int dt = 0; dt < 4; dt++) {
    int col = h * DHEAD + dt * 16 + l16;
#pragma unroll
    for (int rr = 0; rr < 4; rr++) {
      int row = b * NSEQ + it * 64 + w * 16 + quad * 4 + rr;
      ao[(size_t)row * DMODEL + col] = (bf16_t)(o[dt][rr] / l_r[rr]);
    }
  }
#undef LOADBIAS
}

// ---------------- launch ----------------
extern "C" void kernel_launch(void* const* d_in, const int* in_sizes, int n_in,
                              void* d_out, int out_size, void* d_ws, size_t ws_size,
                              hipStream_t stream) {
  const float* x     = (const float*)d_in[0];
  const float* cd    = (const float*)d_in[1];
  const float* Wqkv  = (const float*)d_in[2];
  const float* Wout  = (const float*)d_in[3];
  const float* bout  = (const float*)d_in[4];
  const float* rel_w = (const float*)d_in[5];
  const float* rel_b = (const float*)d_in[6];
  float* out = (float*)d_out;

  char* ws = (char*)d_ws;
  const size_t M = (size_t)BATCH * NSEQ;                 // 8192
  bf16_t* xb    = (bf16_t*)ws;                           // 8 MB
  bf16_t* WqkvT = (bf16_t*)(ws + 8388608);
  bf16_t* WoutT = (bf16_t*)(ws + 8388608 + 1572864);
  bf16_t* qkv   = (bf16_t*)(ws + 8388608 + 1572864 + 524288);
  bf16_t* ao    = (bf16_t*)(ws + 8388608 + 1572864 + 524288 + 25165824);

  cvt_bf16_kernel<<<(int)(M * DMODEL / 4 / 256), 256, 0, stream>>>(x, xb, (int)(M * DMODEL / 4));
  cvt_transpose_kernel<<<dim3(QKVN / 64, DMODEL / 64), 256, 0, stream>>>(Wqkv, WqkvT, DMODEL, QKVN);
  cvt_transpose_kernel<<<dim3(DMODEL / 64, DMODEL / 64), 256, 0, stream>>>(Wout, WoutT, DMODEL, DMODEL);

  // gemm0: 128x64 tiles -> grid (64,24) = 1536 blocks = 6 blocks/CU
  gemm_kernel<128, 64, 0, 0><<<dim3(M / 128, QKVN / 64), 256, 0, stream>>>(
      xb, WqkvT, (void*)qkv, nullptr, (int)M, QKVN, DMODEL);

  attn_kernel<<<BATCH * 32 * HEADS, 256, 0, stream>>>(qkv, cd, rel_w, rel_b, ao);

  // gemm1: 64x64 tiles -> grid (128,8) = 1024 blocks = 4 blocks/CU
  // (was 128x128 -> 256 blocks = 1 block/CU: fully latency-exposed K-loop)
  gemm_kernel<64, 64, 1, 1><<<dim3(M / 64, DMODEL / 64), 256, 0, stream>>>(
      ao, WoutT, (void*)out, bout, (int)M, DMODEL, DMODEL);
}